// Round 1
// baseline (352.022 us; speedup 1.0000x reference)
//
#include <hip/hip_runtime.h>
#include <math.h>

// Problem constants
#define NN    8
#define EE    56
#define CIMG  1024
#define H1F   512
#define H2F   256
#define NODE  2048
#define TT    128
#define ACT   4

// Workspace layout (float offsets)
#define OFF_H1   0        // 8*512   = 4096   (h1 pre-bias accumulator)
#define OFF_H2   4096     // 8*256   = 2048   (h2 pre-bias accumulator)
#define OFF_XA   6144     // 8*2048  = 16384  (x pre-bias accumulator)
#define OFF_Y2   22528    // 8*128*4 = 4096   (Y2 accumulator)
#define OFF_X    26624    // 16384            (finalized x = sigmoid)
#define OFF_EW   43008    // 56*128  = 7168   (relu(e@pr_w1+pr_b1))
#define WS_ZERO_FLOATS 26624   // zero h1acc, h2acc, xacc, y2acc

// ---------------------------------------------------------------------------
// Generic skinny GEMM: out[8, F] += act(X[8, K]) @ W[K, F], split-K atomics.
// grid = (F/256, K/64), block = 256. Each thread owns one output column for
// all 8 rows over a 64-wide K chunk. act = relu(v + prevBias) if applyRelu.
// ---------------------------------------------------------------------------
__global__ __launch_bounds__(256) void gemm8_atomic(
    const float* __restrict__ X, int ldx,
    const float* __restrict__ prevBias, int applyRelu,
    const float* __restrict__ W, int F,
    float* __restrict__ out)
{
    __shared__ float xin[8 * 64];
    const int tid = threadIdx.x;
    const int kbeg = blockIdx.y * 64;

    for (int idx = tid; idx < 8 * 64; idx += 256) {
        int r = idx >> 6, kk = idx & 63;
        float v = X[r * ldx + kbeg + kk];
        if (applyRelu) { v += prevBias[kbeg + kk]; v = v > 0.f ? v : 0.f; }
        xin[idx] = v;
    }
    __syncthreads();

    const int c = blockIdx.x * 256 + tid;
    float acc[8] = {0, 0, 0, 0, 0, 0, 0, 0};
    const float* Wp = W + (size_t)kbeg * F + c;
#pragma unroll 4
    for (int kk = 0; kk < 64; ++kk) {
        float w = Wp[(size_t)kk * F];
#pragma unroll
        for (int r = 0; r < 8; ++r) acc[r] += xin[r * 64 + kk] * w;
    }
#pragma unroll
    for (int r = 0; r < 8; ++r) atomicAdd(&out[r * F + c], acc[r]);
}

// ---------------------------------------------------------------------------
// x = sigmoid(xacc + ncp_b3)   (16384 elems, grid 64 x 256)
// ---------------------------------------------------------------------------
__global__ __launch_bounds__(256) void finalize_x(
    const float* __restrict__ xacc, const float* __restrict__ b3,
    float* __restrict__ x)
{
    int i = blockIdx.x * 256 + threadIdx.x;
    float v = xacc[i] + b3[i & (NODE - 1)];
    x[i] = 1.f / (1.f + expf(-v));
}

// ---------------------------------------------------------------------------
// Edge path (batch 0 only), single block: attr -> g1 -> g2 -> g3 -> e -> ew
// ---------------------------------------------------------------------------
__global__ __launch_bounds__(256) void edge_kernel(
    const float* __restrict__ bbox, const float* __restrict__ dir,
    const float* __restrict__ pri,
    const float* __restrict__ ew1, const float* __restrict__ eb1,
    const float* __restrict__ ew2, const float* __restrict__ eb2,
    const float* __restrict__ ew3, const float* __restrict__ eb3,
    const float* __restrict__ pw1, const float* __restrict__ pb1,
    float* __restrict__ ew_out)
{
    __shared__ float attr[8][8];
    __shared__ float g1[8][256];
    __shared__ float g2[8][64];
    __shared__ float ebuf[56][4];
    const int tid = threadIdx.x;

    if (tid < 64) {
        int r = tid >> 3, j = tid & 7;
        attr[r][j] = (j < 4) ? bbox[r * 4 + j] * (1.0f / 1024.0f)
                             : dir[r * 4 + (j - 4)];
    }
    __syncthreads();

    // g1[8][256]: thread -> column
    {
        int cc = tid;
        for (int r = 0; r < 8; ++r) {
            float s = eb1[cc];
#pragma unroll
            for (int j = 0; j < 8; ++j) s += attr[r][j] * ew1[j * 256 + cc];
            g1[r][cc] = s > 0.f ? s : 0.f;
        }
    }
    __syncthreads();

    // g2[8][64]: 512 outputs
    for (int idx = tid; idx < 512; idx += 256) {
        int r = idx >> 6, cc = idx & 63;
        float s = eb2[cc];
        for (int j = 0; j < 256; ++j) s += g1[r][j] * ew2[j * 64 + cc];
        g2[r][cc] = s > 0.f ? s : 0.f;
    }
    __syncthreads();

    // g3 flat [8*21] == e channels 0..2 flat [56*3]
    if (tid < 168) {
        int r = tid / 21, q = tid % 21;
        float s = eb3[q];
        for (int j = 0; j < 64; ++j) s += g2[r][j] * ew3[j * 21 + q];
        ebuf[tid / 3][tid % 3] = 1.f / (1.f + expf(-s));
    }
    // HigherPri channel: reference quirk — compares pri[i] vs pri[e%7]
    if (tid < 56) {
        int i = tid / 7, j = tid % 7;
        ebuf[tid][3] = (pri[i] > pri[j]) ? 1.f : 0.f;
    }
    __syncthreads();

    // ew[56][128] = relu(e @ pr_w1 + pr_b1)
    for (int idx = tid; idx < 56 * 128; idx += 256) {
        int e = idx >> 7, t = idx & 127;
        float s = pb1[t];
#pragma unroll
        for (int ch = 0; ch < 4; ++ch) s += ebuf[e][ch] * pw1[ch * 128 + t];
        ew_out[idx] = s > 0.f ? s : 0.f;
    }
}

// ---------------------------------------------------------------------------
// Y2[s][t][o] += sum_c x[s][c] * pr_w2[t][c*4+o]
// grid = (128 t, 2 c-halves), block = 256. x chunk staged in LDS (32 KB).
// ---------------------------------------------------------------------------
__global__ __launch_bounds__(256) void y2_kernel(
    const float* __restrict__ x, const float* __restrict__ pw2,
    float* __restrict__ y2acc)
{
    const int t = blockIdx.x;
    const int half = blockIdx.y;
    __shared__ float shx[8 * 1024];
    __shared__ float red[256];
    const int tid = threadIdx.x;

    for (int i = tid; i < 8192; i += 256) {
        int r = i >> 10, cl = i & 1023;
        shx[i] = x[r * 2048 + half * 1024 + cl];
    }
    __syncthreads();

    float part[8] = {0, 0, 0, 0, 0, 0, 0, 0};
    const float* row = pw2 + (size_t)t * 8192 + half * 4096;
#pragma unroll 4
    for (int i = 0; i < 16; ++i) {
        int j = tid + i * 256;          // 0..4095; o = j&3 = tid&3 (fixed)
        float w = row[j];
        int cl = j >> 2;
#pragma unroll
        for (int s = 0; s < 8; ++s) part[s] += shx[s * 1024 + cl] * w;
    }

    for (int s = 0; s < 8; ++s) {
        __syncthreads();
        red[tid] = part[s];
        __syncthreads();
        for (int off = 128; off >= 4; off >>= 1) {
            if (tid < off) red[tid] += red[tid + off];
            __syncthreads();
        }
        if (tid < 4) atomicAdd(&y2acc[(s * 128 + t) * 4 + tid], red[tid]);
    }
}

// ---------------------------------------------------------------------------
// Final: dotb = x@pr_b2-view, xr = x@root, msg/agg over 56 edges, output [8,4]
// ---------------------------------------------------------------------------
__global__ __launch_bounds__(256) void final_kernel(
    const float* __restrict__ x, const float* __restrict__ pb2,
    const float* __restrict__ root, const float* __restrict__ bias,
    const float* __restrict__ ew, const float* __restrict__ y2,
    float* __restrict__ out)
{
    __shared__ float sdotb[8][4], sxr[8][4], sagg[8][4];
    const int tid = threadIdx.x;
    const int lane = tid & 63, wave = tid >> 6;

    if (tid < 32) {
        int s = tid >> 2, o = tid & 3;
        sdotb[s][o] = 0.f; sxr[s][o] = 0.f; sagg[s][o] = 0.f;
    }
    __syncthreads();

    // Phase A: dotb[s][o] = sum_c x[s][c]*pb2[c*4+o]; xr likewise with root
    for (int s = 0; s < 8; ++s) {
        float pd[4] = {0, 0, 0, 0}, pr[4] = {0, 0, 0, 0};
        for (int c = tid; c < 2048; c += 256) {
            float xv = x[s * 2048 + c];
            float4 bv = ((const float4*)pb2)[c];
            float4 rv = ((const float4*)root)[c];
            pd[0] += xv * bv.x; pd[1] += xv * bv.y;
            pd[2] += xv * bv.z; pd[3] += xv * bv.w;
            pr[0] += xv * rv.x; pr[1] += xv * rv.y;
            pr[2] += xv * rv.z; pr[3] += xv * rv.w;
        }
#pragma unroll
        for (int o = 0; o < 4; ++o) {
            for (int off = 32; off; off >>= 1) {
                pd[o] += __shfl_xor(pd[o], off);
                pr[o] += __shfl_xor(pr[o], off);
            }
        }
        if (lane == 0) {
#pragma unroll
            for (int o = 0; o < 4; ++o) {
                atomicAdd(&sdotb[s][o], pd[o]);
                atomicAdd(&sxr[s][o], pr[o]);
            }
        }
    }

    // Phase B: msg[e][o] = sum_t ew[e][t]*Y2[src][t][o]; agg by dst
    for (int e = wave; e < 56; e += 4) {
        int i = e / 7, jj = e % 7;
        int dst = jj + (jj >= i ? 1 : 0);
        int src = i;
        float pm[4] = {0, 0, 0, 0};
        for (int t = lane; t < 128; t += 64) {
            float w = ew[e * 128 + t];
            const float* yp = &y2[(src * 128 + t) * 4];
            pm[0] += w * yp[0]; pm[1] += w * yp[1];
            pm[2] += w * yp[2]; pm[3] += w * yp[3];
        }
#pragma unroll
        for (int o = 0; o < 4; ++o)
            for (int off = 32; off; off >>= 1) pm[o] += __shfl_xor(pm[o], off);
        if (lane == 0) {
#pragma unroll
            for (int o = 0; o < 4; ++o) atomicAdd(&sagg[dst][o], pm[o]);
        }
    }
    __syncthreads();

    if (tid < 32) {
        int n = tid >> 2, o = tid & 3;
        float totd = 0.f;
#pragma unroll
        for (int s = 0; s < 8; ++s) totd += sdotb[s][o];
        out[tid] = sagg[n][o] + (totd - sdotb[n][o]) + sxr[n][o] + bias[o];
    }
}

// ---------------------------------------------------------------------------
extern "C" void kernel_launch(void* const* d_in, const int* in_sizes, int n_in,
                              void* d_out, int out_size, void* d_ws, size_t ws_size,
                              hipStream_t stream)
{
    (void)in_sizes; (void)n_in; (void)out_size; (void)ws_size;

    const float* roi    = (const float*)d_in[0];   // [B,8,1024] -> batch 0 only
    const float* bbox   = (const float*)d_in[1];
    const float* dirs   = (const float*)d_in[2];
    const float* pri    = (const float*)d_in[3];
    const float* ncp_w1 = (const float*)d_in[4];
    const float* ncp_b1 = (const float*)d_in[5];
    const float* ncp_w2 = (const float*)d_in[6];
    const float* ncp_b2 = (const float*)d_in[7];
    const float* ncp_w3 = (const float*)d_in[8];
    const float* ncp_b3 = (const float*)d_in[9];
    const float* ep_w1  = (const float*)d_in[10];
    const float* ep_b1  = (const float*)d_in[11];
    const float* ep_w2  = (const float*)d_in[12];
    const float* ep_b2  = (const float*)d_in[13];
    const float* ep_w3  = (const float*)d_in[14];
    const float* ep_b3  = (const float*)d_in[15];
    const float* pr_w1  = (const float*)d_in[16];
    const float* pr_b1  = (const float*)d_in[17];
    const float* pr_w2  = (const float*)d_in[18];
    const float* pr_b2  = (const float*)d_in[19];
    const float* root   = (const float*)d_in[20];
    const float* bias   = (const float*)d_in[21];

    float* ws    = (float*)d_ws;
    float* h1acc = ws + OFF_H1;
    float* h2acc = ws + OFF_H2;
    float* xacc  = ws + OFF_XA;
    float* y2acc = ws + OFF_Y2;
    float* x     = ws + OFF_X;
    float* ewbuf = ws + OFF_EW;

    // Zero all atomic accumulators (ws is poisoned 0xAA before every launch)
    hipMemsetAsync(d_ws, 0, WS_ZERO_FLOATS * sizeof(float), stream);

    dim3 blk(256);
    // Node MLP on batch 0 only
    gemm8_atomic<<<dim3(2, 16), blk, 0, stream>>>(roi, CIMG, nullptr, 0,
                                                  ncp_w1, H1F, h1acc);
    gemm8_atomic<<<dim3(1, 8), blk, 0, stream>>>(h1acc, H1F, ncp_b1, 1,
                                                 ncp_w2, H2F, h2acc);
    gemm8_atomic<<<dim3(8, 4), blk, 0, stream>>>(h2acc, H2F, ncp_b2, 1,
                                                 ncp_w3, NODE, xacc);
    finalize_x<<<64, blk, 0, stream>>>(xacc, ncp_b3, x);

    // Edge path (independent; tiny)
    edge_kernel<<<1, blk, 0, stream>>>(bbox, dirs, pri, ep_w1, ep_b1, ep_w2,
                                       ep_b2, ep_w3, ep_b3, pr_w1, pr_b1,
                                       ewbuf);

    // Y2 = x @ pr_w2 (reshaped), the only 4 MB read
    y2_kernel<<<dim3(128, 2), blk, 0, stream>>>(x, pr_w2, y2acc);

    // msg/agg + x@root + bias -> out[8][4]
    final_kernel<<<1, blk, 0, stream>>>(x, pr_b2, root, bias, ewbuf, y2acc,
                                        (float*)d_out);
}

// Round 2
// 262.484 us; speedup vs baseline: 1.3411x; 1.3411x over previous
//
#include <hip/hip_runtime.h>
#include <math.h>

// Problem constants
#define CIMG  1024
#define H1F   512
#define H2F   256
#define NODE  2048

// Workspace layout (float offsets) — no zero-init needed anywhere:
// every element is written before it is read (split-K partial buffers).
#define OFF_H1P  0        // h1part [16][8][512]  = 65536
#define OFF_H2P  65536    // h2part [16][8][256]  = 32768
#define OFF_XP   98304    // xpart  [4][8][2048]  = 65536
#define OFF_Y2P  163840   // y2part [2][8][128][4]= 8192
#define OFF_EW   172032   // ew     [56][128]     = 7168

// ---------------------------------------------------------------------------
// K1: layer1 split-K partials (blocks 0..31) + full edge path (block 32).
//   L1: h1part[kc][r][c] = roi0[r, kc*64..+64] @ ncp_w1[., c-chunk]
//   edge: attr -> g1 -> g2 -> sigmoid e -> ew = relu(e @ pr_w1 + pr_b1)
// ---------------------------------------------------------------------------
__global__ __launch_bounds__(256) void k1_l1_edge(
    const float* __restrict__ roi, const float* __restrict__ w1,
    const float* __restrict__ bbox, const float* __restrict__ dir,
    const float* __restrict__ pri,
    const float* __restrict__ ew1, const float* __restrict__ eb1,
    const float* __restrict__ ew2, const float* __restrict__ eb2,
    const float* __restrict__ ew3, const float* __restrict__ eb3,
    const float* __restrict__ pw1, const float* __restrict__ pb1,
    float* __restrict__ h1part, float* __restrict__ ew_out)
{
    __shared__ float smem[2912];   // L1: xin[512]; edge: carved below
    const int tid = threadIdx.x;
    const int b = blockIdx.x;

    if (b < 32) {
        // ---- layer-1 split-K block: kchunk = b>>1, cchunk = b&1 ----
        float* xin = smem;                    // [8][64]
        const int kbeg = (b >> 1) * 64;
        const int cbase = (b & 1) * 256;
        for (int idx = tid; idx < 512; idx += 256) {
            int r = idx >> 6, kk = idx & 63;
            xin[idx] = roi[r * CIMG + kbeg + kk];
        }
        __syncthreads();
        const int c = cbase + tid;
        float acc[8] = {0, 0, 0, 0, 0, 0, 0, 0};
        const float* Wp = w1 + (size_t)kbeg * H1F + c;
#pragma unroll 4
        for (int kk = 0; kk < 64; ++kk) {
            float w = Wp[(size_t)kk * H1F];
#pragma unroll
            for (int r = 0; r < 8; ++r) acc[r] += xin[r * 64 + kk] * w;
        }
        float* outp = h1part + (b >> 1) * 4096;  // [8][512] slice
#pragma unroll
        for (int r = 0; r < 8; ++r) outp[r * H1F + c] = acc[r];
        return;
    }

    // ---- edge path (single block) ----
    float* attr = smem;            // [8][8]   = 64
    float* g1   = smem + 64;       // [8][256] = 2048
    float* g2   = smem + 2112;     // [8][64]  = 512
    float* ebuf = smem + 2624;     // [56][4]  = 224

    if (tid < 64) {
        int r = tid >> 3, j = tid & 7;
        attr[r * 8 + j] = (j < 4) ? bbox[r * 4 + j] * (1.0f / 1024.0f)
                                  : dir[r * 4 + (j - 4)];
    }
    __syncthreads();

    {   // g1[8][256]
        int cc = tid;
        for (int r = 0; r < 8; ++r) {
            float s = eb1[cc];
#pragma unroll
            for (int j = 0; j < 8; ++j) s += attr[r * 8 + j] * ew1[j * 256 + cc];
            g1[r * 256 + cc] = s > 0.f ? s : 0.f;
        }
    }
    __syncthreads();

    for (int idx = tid; idx < 512; idx += 256) {   // g2[8][64]
        int r = idx >> 6, cc = idx & 63;
        float s = eb2[cc];
        for (int j = 0; j < 256; ++j) s += g1[r * 256 + j] * ew2[j * 64 + cc];
        g2[idx] = s > 0.f ? s : 0.f;
    }
    __syncthreads();

    if (tid < 168) {   // g3 flat [8*21] == e channels 0..2 flat [56*3]
        int r = tid / 21, q = tid % 21;
        float s = eb3[q];
        for (int j = 0; j < 64; ++j) s += g2[r * 64 + j] * ew3[j * 21 + q];
        ebuf[(tid / 3) * 4 + (tid % 3)] = 1.f / (1.f + expf(-s));
    }
    if (tid < 56) {    // HigherPri quirk: pri[e/7] > pri[e%7]
        ebuf[tid * 4 + 3] = (pri[tid / 7] > pri[tid % 7]) ? 1.f : 0.f;
    }
    __syncthreads();

    for (int idx = tid; idx < 56 * 128; idx += 256) {  // ew = relu(e@pw1+pb1)
        int e = idx >> 7, t = idx & 127;
        float s = pb1[t];
#pragma unroll
        for (int ch = 0; ch < 4; ++ch) s += ebuf[e * 4 + ch] * pw1[ch * 128 + t];
        ew_out[idx] = s > 0.f ? s : 0.f;
    }
}

// ---------------------------------------------------------------------------
// K2: layer2. 16 blocks, kchunk=32 over K=512. Stages relu(b1 + sum of 16
// h1 partials) into LDS, writes h2part[b][8][256].
// ---------------------------------------------------------------------------
__global__ __launch_bounds__(256) void k2_l2(
    const float* __restrict__ h1part, const float* __restrict__ b1,
    const float* __restrict__ w2, float* __restrict__ h2part)
{
    __shared__ float xin[8 * 32];
    const int tid = threadIdx.x;
    const int kbeg = blockIdx.x * 32;

    if (tid < 256) {
        int r = tid >> 5, kk = tid & 31;
        int k = kbeg + kk;
        float v = b1[k];
#pragma unroll
        for (int p = 0; p < 16; ++p) v += h1part[p * 4096 + r * H1F + k];
        xin[r * 32 + kk] = v > 0.f ? v : 0.f;
    }
    __syncthreads();

    const int c = tid;
    float acc[8] = {0, 0, 0, 0, 0, 0, 0, 0};
    const float* Wp = w2 + (size_t)kbeg * H2F + c;
#pragma unroll 4
    for (int kk = 0; kk < 32; ++kk) {
        float w = Wp[(size_t)kk * H2F];
#pragma unroll
        for (int r = 0; r < 8; ++r) acc[r] += xin[r * 32 + kk] * w;
    }
    float* outp = h2part + blockIdx.x * 2048;
#pragma unroll
    for (int r = 0; r < 8; ++r) outp[r * H2F + c] = acc[r];
}

// ---------------------------------------------------------------------------
// K3: layer3. 32 blocks = 4 kchunks(64) x 8 cchunks(256). Stages relu(b2 +
// sum of 16 h2 partials), writes xpart[kc][8][2048] (pre-bias, pre-sigmoid).
// ---------------------------------------------------------------------------
__global__ __launch_bounds__(256) void k3_l3(
    const float* __restrict__ h2part, const float* __restrict__ b2,
    const float* __restrict__ w3, float* __restrict__ xpart)
{
    __shared__ float xin[8 * 64];
    const int tid = threadIdx.x;
    const int kc = blockIdx.x >> 3;
    const int cbase = (blockIdx.x & 7) * 256;
    const int kbeg = kc * 64;

    for (int idx = tid; idx < 512; idx += 256) {
        int r = idx >> 6, kk = idx & 63;
        int k = kbeg + kk;
        float v = b2[k];
#pragma unroll
        for (int p = 0; p < 16; ++p) v += h2part[p * 2048 + r * H2F + k];
        xin[idx] = v > 0.f ? v : 0.f;
    }
    __syncthreads();

    const int c = cbase + tid;
    float acc[8] = {0, 0, 0, 0, 0, 0, 0, 0};
    const float* Wp = w3 + (size_t)kbeg * NODE + c;
#pragma unroll 4
    for (int kk = 0; kk < 64; ++kk) {
        float w = Wp[(size_t)kk * NODE];
#pragma unroll
        for (int r = 0; r < 8; ++r) acc[r] += xin[r * 64 + kk] * w;
    }
    float* outp = xpart + kc * 16384;
#pragma unroll
    for (int r = 0; r < 8; ++r) outp[r * NODE + c] = acc[r];
}

// ---------------------------------------------------------------------------
// K4: Y2 partials. grid (128 t, 2 half). Finalizes x = sigmoid(b3 + sum of 4
// xparts) for its c-half into LDS, then Y2part[half][s][t][o] direct write.
// ---------------------------------------------------------------------------
__global__ __launch_bounds__(256) void k4_y2(
    const float* __restrict__ xpart, const float* __restrict__ b3,
    const float* __restrict__ pw2, float* __restrict__ y2part)
{
    const int t = blockIdx.x;
    const int half = blockIdx.y;
    __shared__ float shx[8 * 1024];
    __shared__ float redbuf[4 * 32];
    const int tid = threadIdx.x;

    for (int i = tid; i < 8192; i += 256) {
        int r = i >> 10, cl = i & 1023;
        int c = half * 1024 + cl;
        float v = b3[c];
#pragma unroll
        for (int p = 0; p < 4; ++p) v += xpart[p * 16384 + r * NODE + c];
        shx[i] = 1.f / (1.f + expf(-v));
    }
    __syncthreads();

    float part[8] = {0, 0, 0, 0, 0, 0, 0, 0};
    const float* row = pw2 + (size_t)t * 8192 + half * 4096;
#pragma unroll 4
    for (int it = 0; it < 16; ++it) {
        int j = tid + it * 256;        // o = j&3 = tid&3 (fixed per thread)
        float w = row[j];
        int cl = j >> 2;
#pragma unroll
        for (int s = 0; s < 8; ++s) part[s] += shx[s * 1024 + cl] * w;
    }

    // reduce the 16 same-o lanes within each wave, then across 4 waves
    const int lane = tid & 63, wave = tid >> 6;
#pragma unroll
    for (int s = 0; s < 8; ++s) {
        part[s] += __shfl_xor(part[s], 4);
        part[s] += __shfl_xor(part[s], 8);
        part[s] += __shfl_xor(part[s], 16);
        part[s] += __shfl_xor(part[s], 32);
    }
    if (lane < 4) {
#pragma unroll
        for (int s = 0; s < 8; ++s) redbuf[wave * 32 + s * 4 + lane] = part[s];
    }
    __syncthreads();
    if (tid < 32) {
        float v = redbuf[tid] + redbuf[32 + tid] + redbuf[64 + tid] + redbuf[96 + tid];
        int s = tid >> 2, o = tid & 3;
        y2part[half * 4096 + (s * 128 + t) * 4 + o] = v;
    }
}

// ---------------------------------------------------------------------------
// K5: final. 1 block x 1024 threads (16 waves).
//   Phase A (wave w -> s=w>>1, half=w&1): dotb[s]=x[s]·pb2-view, xr[s]=x[s]·root,
//     recomputing x on the fly from xpart.
//   Phase B: msg over 56 edges from ew and Y2 (= y2part0 + y2part1).
//   out[n][o] = agg[n][o] + (totdotb - dotb[n][o]) + xr[n][o] + bias[o]
// ---------------------------------------------------------------------------
__global__ __launch_bounds__(1024) void k5_final(
    const float* __restrict__ xpart, const float* __restrict__ b3,
    const float* __restrict__ pb2, const float* __restrict__ root,
    const float* __restrict__ bias, const float* __restrict__ ew,
    const float* __restrict__ y2part, float* __restrict__ out)
{
    __shared__ float sdotb[8][2][4], sxr[8][2][4], sagg[8][4];
    const int tid = threadIdx.x;
    const int lane = tid & 63, wave = tid >> 6;

    if (tid < 32) sagg[tid >> 2][tid & 3] = 0.f;
    __syncthreads();

    // ---- Phase A ----
    {
        const int s = wave >> 1, half = wave & 1;
        float pd[4] = {0, 0, 0, 0}, pr[4] = {0, 0, 0, 0};
#pragma unroll 4
        for (int k = 0; k < 16; ++k) {
            int c = half * 1024 + k * 64 + lane;
            float v = b3[c];
#pragma unroll
            for (int p = 0; p < 4; ++p) v += xpart[p * 16384 + s * NODE + c];
            float xv = 1.f / (1.f + expf(-v));
            float4 bv = ((const float4*)pb2)[c];
            float4 rv = ((const float4*)root)[c];
            pd[0] += xv * bv.x; pd[1] += xv * bv.y;
            pd[2] += xv * bv.z; pd[3] += xv * bv.w;
            pr[0] += xv * rv.x; pr[1] += xv * rv.y;
            pr[2] += xv * rv.z; pr[3] += xv * rv.w;
        }
#pragma unroll
        for (int o = 0; o < 4; ++o) {
            for (int off = 32; off; off >>= 1) {
                pd[o] += __shfl_xor(pd[o], off);
                pr[o] += __shfl_xor(pr[o], off);
            }
        }
        if (lane == 0) {
#pragma unroll
            for (int o = 0; o < 4; ++o) {
                sdotb[s][half][o] = pd[o];
                sxr[s][half][o] = pr[o];
            }
        }
    }

    // ---- Phase B: edges e = wave, wave+16, ... ----
    const float* y2a = y2part;
    const float* y2b = y2part + 4096;
    for (int e = wave; e < 56; e += 16) {
        int i = e / 7, jj = e % 7;
        int dst = jj + (jj >= i ? 1 : 0);
        int src = i;
        float pm[4] = {0, 0, 0, 0};
#pragma unroll
        for (int half = 0; half < 2; ++half) {
            int t = lane + half * 64;
            float w = ew[e * 128 + t];
            float4 ya = ((const float4*)y2a)[src * 128 + t];
            float4 yb = ((const float4*)y2b)[src * 128 + t];
            pm[0] += w * (ya.x + yb.x); pm[1] += w * (ya.y + yb.y);
            pm[2] += w * (ya.z + yb.z); pm[3] += w * (ya.w + yb.w);
        }
#pragma unroll
        for (int o = 0; o < 4; ++o)
            for (int off = 32; off; off >>= 1) pm[o] += __shfl_xor(pm[o], off);
        if (lane == 0) {
#pragma unroll
            for (int o = 0; o < 4; ++o) atomicAdd(&sagg[dst][o], pm[o]);
        }
    }
    __syncthreads();

    if (tid < 32) {
        int n = tid >> 2, o = tid & 3;
        float totd = 0.f;
#pragma unroll
        for (int s = 0; s < 8; ++s) totd += sdotb[s][0][o] + sdotb[s][1][o];
        float dn = sdotb[n][0][o] + sdotb[n][1][o];
        float xr = sxr[n][0][o] + sxr[n][1][o];
        out[tid] = sagg[n][o] + (totd - dn) + xr + bias[o];
    }
}

// ---------------------------------------------------------------------------
extern "C" void kernel_launch(void* const* d_in, const int* in_sizes, int n_in,
                              void* d_out, int out_size, void* d_ws, size_t ws_size,
                              hipStream_t stream)
{
    (void)in_sizes; (void)n_in; (void)out_size; (void)ws_size;

    const float* roi    = (const float*)d_in[0];   // [B,8,1024] -> batch 0 only
    const float* bbox   = (const float*)d_in[1];
    const float* dirs   = (const float*)d_in[2];
    const float* pri    = (const float*)d_in[3];
    const float* ncp_w1 = (const float*)d_in[4];
    const float* ncp_b1 = (const float*)d_in[5];
    const float* ncp_w2 = (const float*)d_in[6];
    const float* ncp_b2 = (const float*)d_in[7];
    const float* ncp_w3 = (const float*)d_in[8];
    const float* ncp_b3 = (const float*)d_in[9];
    const float* ep_w1  = (const float*)d_in[10];
    const float* ep_b1  = (const float*)d_in[11];
    const float* ep_w2  = (const float*)d_in[12];
    const float* ep_b2  = (const float*)d_in[13];
    const float* ep_w3  = (const float*)d_in[14];
    const float* ep_b3  = (const float*)d_in[15];
    const float* pr_w1  = (const float*)d_in[16];
    const float* pr_b1  = (const float*)d_in[17];
    const float* pr_w2  = (const float*)d_in[18];
    const float* pr_b2  = (const float*)d_in[19];
    const float* root   = (const float*)d_in[20];
    const float* bias   = (const float*)d_in[21];

    float* ws     = (float*)d_ws;
    float* h1part = ws + OFF_H1P;
    float* h2part = ws + OFF_H2P;
    float* xpart  = ws + OFF_XP;
    float* y2part = ws + OFF_Y2P;
    float* ewbuf  = ws + OFF_EW;

    dim3 blk(256);
    k1_l1_edge<<<33, blk, 0, stream>>>(roi, ncp_w1, bbox, dirs, pri,
                                       ep_w1, ep_b1, ep_w2, ep_b2, ep_w3, ep_b3,
                                       pr_w1, pr_b1, h1part, ewbuf);
    k2_l2<<<16, blk, 0, stream>>>(h1part, ncp_b1, ncp_w2, h2part);
    k3_l3<<<32, blk, 0, stream>>>(h2part, ncp_b2, ncp_w3, xpart);
    k4_y2<<<dim3(128, 2), blk, 0, stream>>>(xpart, ncp_b3, pr_w2, y2part);
    k5_final<<<1, dim3(1024), 0, stream>>>(xpart, ncp_b3, pr_b2, root, bias,
                                           ewbuf, y2part, (float*)d_out);
}